// Round 3
// baseline (1204.122 us; speedup 1.0000x reference)
//
#include <hip/hip_runtime.h>
#include <hip/hip_cooperative_groups.h>

namespace cg = cooperative_groups;

// Problem constants (fixed by setup_inputs)
constexpr int NPTS = 16384;
constexpr int KNB  = 9;
constexpr int CDIM = 16;
constexpr int HDIM = 32;

// Spatial grid: FIXED bounds (data is N(0,1); outliers are clamped into edge
// cells, which keeps the search EXACT for arbitrary inputs — edge cells own
// all points beyond the boundary, and clipped sides count as fully covered).
constexpr int   G    = 32;
constexpr int   GC   = G * G;           // 1024 cells
constexpr float GMIN = -3.3f;
constexpr float GMAX =  3.3f;
constexpr float CW   = (GMAX - GMIN) / G;
constexpr float INVW = G / (GMAX - GMIN);
constexpr float FBIG = 3.0e38f;

constexpr int BLK  = 64;                // one wave per block
constexpr int NBLK = NPTS / BLK;        // 256 blocks -> 1 per CU, co-resident

// ---------------------------------------------------------------------------
// Register-resident top-9 (smallest d2). Arrays indexed only with
// compile-time constants -> stay in VGPRs.
// ---------------------------------------------------------------------------
struct TopK {
    float d[KNB];
    int   id[KNB];
    float dw;

    __device__ __forceinline__ void init() {
#pragma unroll
        for (int s = 0; s < KNB; ++s) { d[s] = FBIG; id[s] = -1; }
        dw = FBIG;
    }
    __device__ __forceinline__ void push(float d2, int j) {
        if (d2 < dw) {
            bool done = false;
#pragma unroll
            for (int s = 0; s < KNB; ++s) {
                bool m = (!done) && (d[s] == dw);
                d[s]  = m ? d2 : d[s];
                id[s] = m ? j  : id[s];
                done  = done || m;
            }
            float m0 = fmaxf(fmaxf(d[0], d[1]), d[2]);
            float m1 = fmaxf(fmaxf(d[3], d[4]), d[5]);
            float m2 = fmaxf(fmaxf(d[6], d[7]), d[8]);
            dw = fmaxf(fmaxf(m0, m1), m2);
        }
    }
};

__device__ __forceinline__ int clampG(int c) { return min(G - 1, max(0, c)); }

// ---------------------------------------------------------------------------
// GCN layer body (non-final): agg = mean_k(hin[nb]); out = agg @ W; ReLU.
// W reads are wave-uniform (loop indices are compile-time) -> scalar loads.
// ---------------------------------------------------------------------------
template <int CIN, int COUT, bool RELU>
__device__ __forceinline__ void gcn_dev(int p, const float* __restrict__ hin,
                                        const int* __restrict__ nb,
                                        const float* __restrict__ W,
                                        float* __restrict__ hout) {
    float agg[CIN];
#pragma unroll
    for (int c = 0; c < CIN; ++c) agg[c] = 0.0f;
#pragma unroll
    for (int k = 0; k < KNB; ++k) {
        const int j = nb[p * KNB + k];
        const float4* r = reinterpret_cast<const float4*>(hin + (size_t)j * CIN);
#pragma unroll
        for (int c4 = 0; c4 < CIN / 4; ++c4) {
            const float4 v = r[c4];
            agg[4 * c4 + 0] += v.x;
            agg[4 * c4 + 1] += v.y;
            agg[4 * c4 + 2] += v.z;
            agg[4 * c4 + 3] += v.w;
        }
    }
#pragma unroll
    for (int c = 0; c < CIN; ++c) agg[c] *= (1.0f / 9.0f);
#pragma unroll
    for (int o = 0; o < COUT; ++o) {
        float acc = 0.0f;
#pragma unroll
        for (int c = 0; c < CIN; ++c) acc = fmaf(agg[c], W[c * COUT + o], acc);
        hout[p * COUT + o] = RELU ? fmaxf(acc, 0.0f) : acc;
    }
}

// ---------------------------------------------------------------------------
// The whole 2-step pipeline as ONE cooperative kernel. Phases separated by
// grid.sync(). Thread tid <-> point tid (original order) for count/scatter,
// binned point tid for knn/gcn.
// ---------------------------------------------------------------------------
__global__ __launch_bounds__(BLK) void mega(const float* __restrict__ seed,
                                            const float* __restrict__ W1,
                                            const float* __restrict__ W2,
                                            const float* __restrict__ W3,
                                            const float* __restrict__ W4,
                                            float* __restrict__ out,
                                            char* __restrict__ wsbase) {
    cg::grid_group grid = cg::this_grid();
    __shared__ int sCS[GC + 1];          // LDS copy of cellStart (4.1 KB)

    // Carve workspace (identical arithmetic in every thread).
    char* w = wsbase;
    auto take = [&](size_t b) -> char* {
        char* p = w; w += (b + 255) & ~(size_t)255; return p;
    };
    int*    cnt0      = (int*)   take(GC * sizeof(int));
    int*    cnt1      = (int*)   take(GC * sizeof(int));
    int*    cellStart = (int*)   take((GC + 1) * sizeof(int));
    int*    cursor    = (int*)   take(GC * sizeof(int));
    float2* bxy       = (float2*)take((size_t)NPTS * sizeof(float2));
    int*    bid       = (int*)   take((size_t)NPTS * sizeof(int));
    float*  xb        = (float*) take((size_t)NPTS * CDIM * sizeof(float));
    int*    nb        = (int*)   take((size_t)NPTS * KNB * sizeof(int));
    float*  hA        = (float*) take((size_t)NPTS * HDIM * sizeof(float));
    float*  hB        = (float*) take((size_t)NPTS * HDIM * sizeof(float));
    float*  x1        = (float*) take((size_t)NPTS * CDIM * sizeof(float));

    const int tid  = blockIdx.x * BLK + threadIdx.x;   // 0..16383
    const int lane = threadIdx.x;

    // P0: zero both steps' cell counts (ws is poisoned 0xAA each call).
    if (tid < GC) { cnt0[tid] = 0; cnt1[tid] = 0; }
    grid.sync();

    for (int step = 0; step < 2; ++step) {
        const float* xin  = step ? x1  : seed;
        float*       xout = step ? out : x1;
        int*         cnt  = step ? cnt1 : cnt0;

        // ---- P1: bin count --------------------------------------------
        const float px = xin[tid * CDIM + 0];
        const float py = xin[tid * CDIM + 1];
        const int   cxp = clampG((int)((px - GMIN) * INVW));
        const int   cyp = clampG((int)((py - GMIN) * INVW));
        const int   mycell = cyp * G + cxp;
        atomicAdd(&cnt[mycell], 1);
        grid.sync();

        // ---- P2: exclusive scan over 1024 cells (block 0 = one wave) --
        if (blockIdx.x == 0) {
            const int base = lane * 16;
            int loc[16];
            int sum = 0;
#pragma unroll
            for (int k = 0; k < 16; ++k) { loc[k] = sum; sum += cnt[base + k]; }
            int inc = sum;
#pragma unroll
            for (int off = 1; off < 64; off <<= 1) {
                const int v = __shfl_up(inc, off);
                if (lane >= off) inc += v;
            }
            const int excl = inc - sum;
#pragma unroll
            for (int k = 0; k < 16; ++k) {
                const int v = excl + loc[k];
                cellStart[base + k] = v;
                cursor[base + k]    = v;
            }
            if (lane == 63) cellStart[GC] = NPTS;
        }
        grid.sync();

        // ---- P3: scatter into binned order ----------------------------
        {
            const int pos = atomicAdd(&cursor[mycell], 1);
            bxy[pos] = make_float2(px, py);
            bid[pos] = tid;
            const float4* src = reinterpret_cast<const float4*>(xin + (size_t)tid * CDIM);
            float4* dst = reinterpret_cast<float4*>(xb + (size_t)pos * CDIM);
            dst[0] = src[0]; dst[1] = src[1]; dst[2] = src[2]; dst[3] = src[3];
        }
        grid.sync();

        // ---- P4: exact kNN via expanding rings, cellStart in LDS ------
        {
            for (int t = lane; t < GC + 1; t += BLK) sCS[t] = cellStart[t];
            __syncthreads();

            const int p = tid;
            const float2 q = bxy[p];
            const float qx = q.x, qy = q.y;
            const int cx = clampG((int)((qx - GMIN) * INVW));
            const int cy = clampG((int)((qy - GMIN) * INVW));

            TopK tk; tk.init();
            const float* bf = reinterpret_cast<const float*>(bxy);

            auto scan_span = [&](int s, int e) {
                int i = s;
                if (i < e && (i & 1)) {
                    const float2 pt = bxy[i];
                    const float dx = qx - pt.x, dy = qy - pt.y;
                    tk.push(fmaf(dx, dx, dy * dy), i); ++i;
                }
                for (; i + 3 < e; i += 4) {
                    const float4 v0 = *reinterpret_cast<const float4*>(bf + 2 * i);
                    const float4 v1 = *reinterpret_cast<const float4*>(bf + 2 * i + 4);
                    const float dx0 = qx - v0.x, dy0 = qy - v0.y;
                    const float dx1 = qx - v0.z, dy1 = qy - v0.w;
                    const float dx2 = qx - v1.x, dy2 = qy - v1.y;
                    const float dx3 = qx - v1.z, dy3 = qy - v1.w;
                    tk.push(fmaf(dx0, dx0, dy0 * dy0), i);
                    tk.push(fmaf(dx1, dx1, dy1 * dy1), i + 1);
                    tk.push(fmaf(dx2, dx2, dy2 * dy2), i + 2);
                    tk.push(fmaf(dx3, dx3, dy3 * dy3), i + 3);
                }
                for (; i < e; ++i) {
                    const float2 pt = bxy[i];
                    const float dx = qx - pt.x, dy = qy - pt.y;
                    tk.push(fmaf(dx, dx, dy * dy), i);
                }
            };
            auto row_span = [&](int y, int x0, int x1) {
                if (y < 0 || y >= G) return;
                x0 = max(x0, 0); x1 = min(x1, G - 1);
                if (x0 > x1) return;
                scan_span(sCS[y * G + x0], sCS[y * G + x1 + 1]);
            };

            row_span(cy - 1, cx - 1, cx + 1);
            row_span(cy,     cx - 1, cx + 1);
            row_span(cy + 1, cx - 1, cx + 1);

            int r = 1;
            while (true) {
                const float dl = (cx - r >= 0) ? fmaxf(qx - (GMIN + (float)(cx - r) * CW), 0.0f) : FBIG;
                const float dr = (cx + r <  G) ? fmaxf((GMIN + (float)(cx + r + 1) * CW) - qx, 0.0f) : FBIG;
                const float db = (cy - r >= 0) ? fmaxf(qy - (GMIN + (float)(cy - r) * CW), 0.0f) : FBIG;
                const float dt = (cy + r <  G) ? fmaxf((GMIN + (float)(cy + r + 1) * CW) - qy, 0.0f) : FBIG;
                const float dmin = fminf(fminf(dl, dr), fminf(db, dt));
                if (tk.dw < FBIG && tk.dw <= dmin * dmin) break;
                ++r;
                if (r >= G) break;
                row_span(cy - r, cx - r, cx + r);
                row_span(cy + r, cx - r, cx + r);
                for (int y = cy - r + 1; y <= cy + r - 1; ++y) {
                    if (y < 0 || y >= G) continue;
                    if (cx - r >= 0) scan_span(sCS[y * G + cx - r], sCS[y * G + cx - r + 1]);
                    if (cx + r <  G) scan_span(sCS[y * G + cx + r], sCS[y * G + cx + r + 1]);
                }
            }
#pragma unroll
            for (int s = 0; s < KNB; ++s) nb[p * KNB + s] = tk.id[s];
        }
        grid.sync();

        // ---- P5..P7: GCN layers 1-3 ----------------------------------
        gcn_dev<CDIM, HDIM, true>(tid, xb, nb, W1, hA);
        grid.sync();
        gcn_dev<HDIM, HDIM, true>(tid, hA, nb, W2, hB);
        grid.sync();
        gcn_dev<HDIM, HDIM, true>(tid, hB, nb, W3, hA);
        grid.sync();

        // ---- P8: layer 4 + residual, scatter back to original order --
        {
            const int p = tid;
            float agg[HDIM];
#pragma unroll
            for (int c = 0; c < HDIM; ++c) agg[c] = 0.0f;
#pragma unroll
            for (int k = 0; k < KNB; ++k) {
                const int j = nb[p * KNB + k];
                const float4* r = reinterpret_cast<const float4*>(hA + (size_t)j * HDIM);
#pragma unroll
                for (int c4 = 0; c4 < HDIM / 4; ++c4) {
                    const float4 v = r[c4];
                    agg[4 * c4 + 0] += v.x;
                    agg[4 * c4 + 1] += v.y;
                    agg[4 * c4 + 2] += v.z;
                    agg[4 * c4 + 3] += v.w;
                }
            }
#pragma unroll
            for (int c = 0; c < HDIM; ++c) agg[c] *= (1.0f / 9.0f);

            float res[CDIM];
#pragma unroll
            for (int o = 0; o < CDIM; ++o) {
                float acc = 0.0f;
#pragma unroll
                for (int c = 0; c < HDIM; ++c) acc = fmaf(agg[c], W4[c * CDIM + o], acc);
                res[o] = xb[p * CDIM + o] + 1e-4f * acc;
            }
            float4* drow = reinterpret_cast<float4*>(xout + (size_t)bid[p] * CDIM);
            const float4* srow = reinterpret_cast<const float4*>(res);
            drow[0] = srow[0]; drow[1] = srow[1]; drow[2] = srow[2]; drow[3] = srow[3];
        }
        grid.sync();
    }
}

// ---------------------------------------------------------------------------
extern "C" void kernel_launch(void* const* d_in, const int* in_sizes, int n_in,
                              void* d_out, int out_size, void* d_ws, size_t ws_size,
                              hipStream_t stream) {
    const float* seed = (const float*)d_in[0];
    const float* W1   = (const float*)d_in[1];
    const float* W2   = (const float*)d_in[2];
    const float* W3   = (const float*)d_in[3];
    const float* W4   = (const float*)d_in[4];
    float* out = (float*)d_out;
    char*  ws  = (char*)d_ws;

    void* args[] = { (void*)&seed, (void*)&W1, (void*)&W2, (void*)&W3,
                     (void*)&W4, (void*)&out, (void*)&ws };
    hipLaunchCooperativeKernel((const void*)mega, dim3(NBLK), dim3(BLK),
                               args, 0, stream);
}

// Round 4
// 905.649 us; speedup vs baseline: 1.3296x; 1.3296x over previous
//
#include <hip/hip_runtime.h>

// Problem constants (fixed by setup_inputs)
constexpr int NPTS = 16384;
constexpr int KNB  = 9;
constexpr int CDIM = 16;
constexpr int HDIM = 32;

// Spatial grid: FIXED bounds (data ~ N(0,1)). Outliers clamp into edge cells;
// search stays EXACT: clamped points lie beyond the scanned block's geometric
// edge, so the ring lower-bound remains valid, and clipped sides are fully
// covered once the ring reaches the grid edge.
constexpr int   G    = 128;
constexpr int   GC   = G * G;            // 16384 cells
constexpr float GMIN = -3.3f;
constexpr float GMAX =  3.3f;
constexpr float CW   = (GMAX - GMIN) / G;
constexpr float INVW = G / (GMAX - GMIN);
constexpr float FBIG = 3.0e38f;

constexpr int LPP = 8;                   // lanes per point in knn

// ---------------------------------------------------------------------------
// Register-resident top-9 (smallest d2). Arrays indexed only with
// compile-time constants -> stay in VGPRs.
// ---------------------------------------------------------------------------
struct TopK {
    float d[KNB];
    int   id[KNB];
    float dw;

    __device__ __forceinline__ void init() {
#pragma unroll
        for (int s = 0; s < KNB; ++s) { d[s] = FBIG; id[s] = -1; }
        dw = FBIG;
    }
    __device__ __forceinline__ void push(float d2, int j) {
        if (d2 < dw) {
            bool done = false;
#pragma unroll
            for (int s = 0; s < KNB; ++s) {
                bool m = (!done) && (d[s] == dw);
                d[s]  = m ? d2 : d[s];
                id[s] = m ? j  : id[s];
                done  = done || m;
            }
            float m0 = fmaxf(fmaxf(d[0], d[1]), d[2]);
            float m1 = fmaxf(fmaxf(d[3], d[4]), d[5]);
            float m2 = fmaxf(fmaxf(d[6], d[7]), d[8]);
            dw = fmaxf(fmaxf(m0, m1), m2);
        }
    }
};

__device__ __forceinline__ int clampG(int c) { return min(G - 1, max(0, c)); }

// ---------------------------------------------------------------------------
// Bin count (fixed box, no bbox pass). 256 blocks x 64 threads.
// ---------------------------------------------------------------------------
__global__ __launch_bounds__(64) void bin_count(const float* __restrict__ x,
                                                int* __restrict__ cnt,
                                                int* __restrict__ cellOf) {
    const int i = blockIdx.x * 64 + threadIdx.x;
    const float2 p = *reinterpret_cast<const float2*>(x + (size_t)i * CDIM);
    const int cx = clampG((int)((p.x - GMIN) * INVW));
    const int cy = clampG((int)((p.y - GMIN) * INVW));
    const int c = cy * G + cx;
    cellOf[i] = c;
    atomicAdd(&cnt[c], 1);
}

// ---------------------------------------------------------------------------
// Exclusive scan over GC=16384 counts (1 block of 1024, 16/thread + LDS
// Hillis-Steele). Writes int cursor (for scatter atomics) and u16 cellStart
// (padded to GC+2 so knn can load it as dwords).
// ---------------------------------------------------------------------------
__global__ __launch_bounds__(1024) void scan_kernel(const int* __restrict__ cnt,
                                                    unsigned short* __restrict__ cs16,
                                                    int* __restrict__ cursor) {
    __shared__ int S[1024];
    const int t = threadIdx.x;
    const int base = t * 16;
    int loc[16];
    int sum = 0;
#pragma unroll
    for (int k = 0; k < 16; ++k) { loc[k] = sum; sum += cnt[base + k]; }
    S[t] = sum;
    __syncthreads();
    for (int off = 1; off < 1024; off <<= 1) {
        const int v = (t >= off) ? S[t - off] : 0;
        __syncthreads();
        S[t] += v;
        __syncthreads();
    }
    const int excl = S[t] - sum;
#pragma unroll
    for (int k = 0; k < 16; ++k) {
        const int v = excl + loc[k];
        cs16[base + k] = (unsigned short)v;
        cursor[base + k] = v;
    }
    if (t == 1023) { cs16[GC] = (unsigned short)NPTS; cs16[GC + 1] = (unsigned short)NPTS; }
}

// ---------------------------------------------------------------------------
// Scatter into binned order: coords (float2), original id, feature row.
// ---------------------------------------------------------------------------
__global__ __launch_bounds__(64) void scatter_kernel(const float* __restrict__ x,
                                                     const int* __restrict__ cellOf,
                                                     int* __restrict__ cursor,
                                                     float2* __restrict__ bxy,
                                                     int* __restrict__ bid,
                                                     float* __restrict__ xb) {
    const int i = blockIdx.x * 64 + threadIdx.x;
    const int c = cellOf[i];
    const int pos = atomicAdd(&cursor[c], 1);
    const float4* src = reinterpret_cast<const float4*>(x + (size_t)i * CDIM);
    float4* dst = reinterpret_cast<float4*>(xb + (size_t)pos * CDIM);
    const float4 v0 = src[0];
    dst[0] = v0; dst[1] = src[1]; dst[2] = src[2]; dst[3] = src[3];
    bxy[pos] = make_float2(v0.x, v0.y);
    bid[pos] = i;
}

// ---------------------------------------------------------------------------
// Exact kNN, 8 lanes per point. 512 blocks x 256 threads = 32 points/block.
// cellStart (u16) cached in LDS (32.8 KB). Lanes stride-8 partition every
// span (duplicate-free union). Conservative group stop: min over lanes of the
// lane-local 9th-best is an upper bound on the group 9th-best, so stopping
// when it is <= dmin^2 is safe (may over-expand a ring, never under-covers).
// 3-step shfl_xor butterfly merges the 8 partial top-9 lists.
// ---------------------------------------------------------------------------
__global__ __launch_bounds__(256) void knn_search(const float2* __restrict__ bxy,
                                                  const unsigned short* __restrict__ cs16,
                                                  int* __restrict__ nb) {
    __shared__ unsigned short sCS[GC + 2];

    // Load the span table as dwords (8193 uints).
    {
        const uint* src = reinterpret_cast<const uint*>(cs16);
        uint* dst = reinterpret_cast<uint*>(sCS);
        for (int t = threadIdx.x; t < (GC + 2) / 2; t += 256) dst[t] = src[t];
    }
    __syncthreads();

    const int g = threadIdx.x >> 3;          // group within block: 0..31
    const int l = threadIdx.x & (LPP - 1);   // lane within group:  0..7
    const int p = blockIdx.x * 32 + g;       // binned point id

    const float2 q = bxy[p];
    const float qx = q.x, qy = q.y;
    const int cx = clampG((int)((qx - GMIN) * INVW));
    const int cy = clampG((int)((qy - GMIN) * INVW));

    TopK tk; tk.init();

    auto scan_span = [&](int s, int e) {
        for (int i = s + l; i < e; i += LPP) {
            const float2 pt = bxy[i];
            const float dx = qx - pt.x;
            const float dy = qy - pt.y;
            tk.push(fmaf(dx, dx, dy * dy), i);
        }
    };
    auto row_span = [&](int y, int x0, int x1) {
        if (y < 0 || y >= G) return;
        x0 = max(x0, 0); x1 = min(x1, G - 1);
        if (x0 > x1) return;
        scan_span((int)sCS[y * G + x0], (int)sCS[y * G + x1 + 1]);
    };

    // r=1 block (3x3)
    row_span(cy - 1, cx - 1, cx + 1);
    row_span(cy,     cx - 1, cx + 1);
    row_span(cy + 1, cx - 1, cx + 1);

    int r = 1;
    while (true) {
        const float dl = (cx - r >= 0) ? fmaxf(qx - (GMIN + (float)(cx - r) * CW), 0.0f) : FBIG;
        const float dr = (cx + r <  G) ? fmaxf((GMIN + (float)(cx + r + 1) * CW) - qx, 0.0f) : FBIG;
        const float db = (cy - r >= 0) ? fmaxf(qy - (GMIN + (float)(cy - r) * CW), 0.0f) : FBIG;
        const float dt = (cy + r <  G) ? fmaxf((GMIN + (float)(cy + r + 1) * CW) - qy, 0.0f) : FBIG;
        const float dmin = fminf(fminf(dl, dr), fminf(db, dt));

        // conservative group-wide bound on the 9th-best distance
        float ub = tk.dw;
        ub = fminf(ub, __shfl_xor(ub, 1));
        ub = fminf(ub, __shfl_xor(ub, 2));
        ub = fminf(ub, __shfl_xor(ub, 4));
        if (ub < FBIG && ub <= dmin * dmin) break;

        ++r;
        if (r >= G) break;                   // full grid covered
        row_span(cy - r, cx - r, cx + r);
        row_span(cy + r, cx - r, cx + r);
        for (int y = cy - r + 1; y <= cy + r - 1; ++y) {
            if (y < 0 || y >= G) continue;
            if (cx - r >= 0) scan_span((int)sCS[y * G + cx - r], (int)sCS[y * G + cx - r + 1]);
            if (cx + r <  G) scan_span((int)sCS[y * G + cx + r], (int)sCS[y * G + cx + r + 1]);
        }
    }

    // Butterfly merge of 8 partial top-9 lists (within the 8-lane group).
#pragma unroll
    for (int m = 1; m < LPP; m <<= 1) {
        float od[KNB]; int oid[KNB];
#pragma unroll
        for (int s = 0; s < KNB; ++s) {
            od[s]  = __shfl_xor(tk.d[s], m);
            oid[s] = __shfl_xor(tk.id[s], m);
        }
#pragma unroll
        for (int s = 0; s < KNB; ++s) tk.push(od[s], oid[s]);
    }

    if (l == 0) {
#pragma unroll
        for (int s = 0; s < KNB; ++s) nb[p * KNB + s] = tk.id[s];
    }
}

// ---------------------------------------------------------------------------
// GCN layer in binned order, thread per point, 256 blocks x 64 threads.
// FINAL fuses residual and scatters back to original order via bid.
// ---------------------------------------------------------------------------
template <int CIN, int COUT, bool RELU, bool FINAL>
__global__ __launch_bounds__(64) void gcn_layer(const float* __restrict__ hin,
                                                const int* __restrict__ nb,
                                                const float* __restrict__ W,
                                                const float* __restrict__ xb,
                                                const int* __restrict__ bid,
                                                float* __restrict__ hout) {
    const int n = blockIdx.x * 64 + threadIdx.x;

    float agg[CIN];
#pragma unroll
    for (int c = 0; c < CIN; ++c) agg[c] = 0.0f;

#pragma unroll
    for (int k = 0; k < KNB; ++k) {
        const int j = nb[n * KNB + k];
        const float4* r = reinterpret_cast<const float4*>(hin + (size_t)j * CIN);
#pragma unroll
        for (int c4 = 0; c4 < CIN / 4; ++c4) {
            const float4 v = r[c4];
            agg[4 * c4 + 0] += v.x;
            agg[4 * c4 + 1] += v.y;
            agg[4 * c4 + 2] += v.z;
            agg[4 * c4 + 3] += v.w;
        }
    }
#pragma unroll
    for (int c = 0; c < CIN; ++c) agg[c] *= (1.0f / 9.0f);

    const int outrow = FINAL ? bid[n] : n;
#pragma unroll
    for (int o = 0; o < COUT; ++o) {
        float acc = 0.0f;
#pragma unroll
        for (int c = 0; c < CIN; ++c) acc = fmaf(agg[c], W[c * COUT + o], acc);
        if (RELU)  acc = fmaxf(acc, 0.0f);
        if (FINAL) acc = xb[n * COUT + o] + 1e-4f * acc;
        hout[outrow * COUT + o] = acc;
    }
}

// ---------------------------------------------------------------------------
extern "C" void kernel_launch(void* const* d_in, const int* in_sizes, int n_in,
                              void* d_out, int out_size, void* d_ws, size_t ws_size,
                              hipStream_t stream) {
    const float* seed = (const float*)d_in[0];
    const float* W1   = (const float*)d_in[1];
    const float* W2   = (const float*)d_in[2];
    const float* W3   = (const float*)d_in[3];
    const float* W4   = (const float*)d_in[4];
    float* out = (float*)d_out;

    char* ws = (char*)d_ws;
    size_t off = 0;
    auto alloc = [&](size_t bytes) -> void* {
        void* p = ws + off;
        off += (bytes + 255) & ~(size_t)255;
        return p;
    };
    int*            cnt    = (int*)   alloc(GC * sizeof(int));
    unsigned short* cs16   = (unsigned short*)alloc((GC + 2) * sizeof(unsigned short));
    int*            cursor = (int*)   alloc(GC * sizeof(int));
    int*            cellOf = (int*)   alloc(NPTS * sizeof(int));
    float2*         bxy    = (float2*)alloc((size_t)NPTS * sizeof(float2));
    int*            bid    = (int*)   alloc(NPTS * sizeof(int));
    float*          xb     = (float*) alloc((size_t)NPTS * CDIM * sizeof(float));
    int*            nb     = (int*)   alloc((size_t)NPTS * KNB * sizeof(int));
    float*          hA     = (float*) alloc((size_t)NPTS * HDIM * sizeof(float));
    float*          hB     = (float*) alloc((size_t)NPTS * HDIM * sizeof(float));
    float*          x1     = (float*) alloc((size_t)NPTS * CDIM * sizeof(float));

    constexpr int NB64 = NPTS / 64;     // 256 blocks of 64

    for (int step = 0; step < 2; ++step) {
        const float* xin  = (step == 0) ? seed : x1;
        float*       xout = (step == 0) ? x1   : out;

        hipMemsetAsync(cnt, 0, GC * sizeof(int), stream);
        bin_count     <<<NB64, 64, 0, stream>>>(xin, cnt, cellOf);
        scan_kernel   <<<1, 1024, 0, stream>>>(cnt, cs16, cursor);
        scatter_kernel<<<NB64, 64, 0, stream>>>(xin, cellOf, cursor, bxy, bid, xb);
        knn_search    <<<512, 256, 0, stream>>>(bxy, cs16, nb);

        gcn_layer<CDIM, HDIM, true,  false><<<NB64, 64, 0, stream>>>(xb, nb, W1, nullptr, nullptr, hA);
        gcn_layer<HDIM, HDIM, true,  false><<<NB64, 64, 0, stream>>>(hA, nb, W2, nullptr, nullptr, hB);
        gcn_layer<HDIM, HDIM, true,  false><<<NB64, 64, 0, stream>>>(hB, nb, W3, nullptr, nullptr, hA);
        gcn_layer<HDIM, CDIM, false, true ><<<NB64, 64, 0, stream>>>(hA, nb, W4, xb, bid, xout);
    }
}

// Round 5
// 453.794 us; speedup vs baseline: 2.6535x; 1.9957x over previous
//
#include <hip/hip_runtime.h>

// Problem constants (fixed by setup_inputs)
constexpr int NPTS = 16384;
constexpr int KNB  = 9;
constexpr int CDIM = 16;
constexpr int HDIM = 32;

// Spatial grid: FIXED bounds (data ~ N(0,1)). Outliers clamp into edge cells;
// search stays EXACT: edge cells own all points beyond the boundary, and a
// clipped side contributes no uncovered region (FBIG) once the block reaches
// the grid edge, because every out-of-box point is stored in the edge cells.
constexpr int   G    = 128;
constexpr int   GC   = G * G;            // 16384 cells
constexpr float GMIN = -3.3f;
constexpr float GMAX =  3.3f;
constexpr float CW   = (GMAX - GMIN) / G;
constexpr float INVW = G / (GMAX - GMIN);
constexpr float FBIG = 3.0e38f;

constexpr int RCAP = 5;                  // ring cap; ~2.6% of points overflow
                                         // to the brute-force straggler pass

// ---------------------------------------------------------------------------
// Register-resident top-9 (smallest d2). Arrays indexed only with
// compile-time constants -> stay in VGPRs.
// ---------------------------------------------------------------------------
struct TopK {
    float d[KNB];
    int   id[KNB];
    float dw;

    __device__ __forceinline__ void init() {
#pragma unroll
        for (int s = 0; s < KNB; ++s) { d[s] = FBIG; id[s] = -1; }
        dw = FBIG;
    }
    __device__ __forceinline__ void push(float d2, int j) {
        if (d2 < dw) {
            bool done = false;
#pragma unroll
            for (int s = 0; s < KNB; ++s) {
                bool m = (!done) && (d[s] == dw);
                d[s]  = m ? d2 : d[s];
                id[s] = m ? j  : id[s];
                done  = done || m;
            }
            float m0 = fmaxf(fmaxf(d[0], d[1]), d[2]);
            float m1 = fmaxf(fmaxf(d[3], d[4]), d[5]);
            float m2 = fmaxf(fmaxf(d[6], d[7]), d[8]);
            dw = fmaxf(fmaxf(m0, m1), m2);
        }
    }
};

__device__ __forceinline__ int clampG(int c) { return min(G - 1, max(0, c)); }

// ---------------------------------------------------------------------------
// Bin count (fixed box). 256 blocks x 64 threads.
// ---------------------------------------------------------------------------
__global__ __launch_bounds__(64) void bin_count(const float* __restrict__ x,
                                                int* __restrict__ cnt,
                                                int* __restrict__ cellOf) {
    const int i = blockIdx.x * 64 + threadIdx.x;
    const float2 p = *reinterpret_cast<const float2*>(x + (size_t)i * CDIM);
    const int cx = clampG((int)((p.x - GMIN) * INVW));
    const int cy = clampG((int)((p.y - GMIN) * INVW));
    const int c = cy * G + cx;
    cellOf[i] = c;
    atomicAdd(&cnt[c], 1);
}

// ---------------------------------------------------------------------------
// Exclusive scan over GC=16384 counts (1 block of 1024). Also RE-ZEROS cnt
// (ready for the next step's bin_count) and zeroes scnt (consumed by this
// step's knn_search/knn_brute) — saves per-step memsets.
// ---------------------------------------------------------------------------
__global__ __launch_bounds__(1024) void scan_kernel(int* __restrict__ cnt,
                                                    unsigned short* __restrict__ cs16,
                                                    int* __restrict__ cursor,
                                                    int* __restrict__ scnt) {
    __shared__ int S[1024];
    const int t = threadIdx.x;
    const int base = t * 16;
    int loc[16];
    int sum = 0;
#pragma unroll
    for (int k = 0; k < 16; ++k) { loc[k] = sum; sum += cnt[base + k]; cnt[base + k] = 0; }
    S[t] = sum;
    __syncthreads();
    for (int off = 1; off < 1024; off <<= 1) {
        const int v = (t >= off) ? S[t - off] : 0;
        __syncthreads();
        S[t] += v;
        __syncthreads();
    }
    const int excl = S[t] - sum;
#pragma unroll
    for (int k = 0; k < 16; ++k) {
        const int v = excl + loc[k];
        cs16[base + k] = (unsigned short)v;
        cursor[base + k] = v;
    }
    if (t == 1023) { cs16[GC] = (unsigned short)NPTS; cs16[GC + 1] = (unsigned short)NPTS; }
    if (t == 0) scnt[0] = 0;
}

// ---------------------------------------------------------------------------
// Scatter into binned order: coords (float2), original id, feature row.
// ---------------------------------------------------------------------------
__global__ __launch_bounds__(64) void scatter_kernel(const float* __restrict__ x,
                                                     const int* __restrict__ cellOf,
                                                     int* __restrict__ cursor,
                                                     float2* __restrict__ bxy,
                                                     int* __restrict__ bid,
                                                     float* __restrict__ xb) {
    const int i = blockIdx.x * 64 + threadIdx.x;
    const int c = cellOf[i];
    const int pos = atomicAdd(&cursor[c], 1);
    const float4* src = reinterpret_cast<const float4*>(x + (size_t)i * CDIM);
    float4* dst = reinterpret_cast<float4*>(xb + (size_t)pos * CDIM);
    const float4 v0 = src[0];
    dst[0] = v0; dst[1] = src[1]; dst[2] = src[2]; dst[3] = src[3];
    bxy[pos] = make_float2(v0.x, v0.y);
    bid[pos] = i;
}

// ---------------------------------------------------------------------------
// Exact capped kNN, ONE LANE PER POINT (lane-local top-9 == exact union, so
// the ring stop-bound fires at the true 9-NN radius — no group merge, no
// under-filled-lane bound bug). Binned-order lanes are spatially coherent ->
// per-wave divergence ~ max span, tight at G=128 (<=~10 pts/cell).
// Points not converged by ring RCAP are appended to the straggler list.
// 64 blocks x 256 threads (4 waves/CU on 64 CUs).
// ---------------------------------------------------------------------------
__global__ __launch_bounds__(256) void knn_search(const float2* __restrict__ bxy,
                                                  const unsigned short* __restrict__ cs16,
                                                  int* __restrict__ nb,
                                                  int* __restrict__ scnt,
                                                  int* __restrict__ slist) {
    __shared__ unsigned short sCS[GC + 2];
    {
        const uint* src = reinterpret_cast<const uint*>(cs16);
        uint* dst = reinterpret_cast<uint*>(sCS);
        for (int t = threadIdx.x; t < (GC + 2) / 2; t += 256) dst[t] = src[t];
    }
    __syncthreads();

    const int p = blockIdx.x * 256 + threadIdx.x;
    const float2 q = bxy[p];
    const float qx = q.x, qy = q.y;
    const int cx = clampG((int)((qx - GMIN) * INVW));
    const int cy = clampG((int)((qy - GMIN) * INVW));

    TopK tk; tk.init();

    auto scan_span = [&](int s, int e) {
        for (int i = s; i < e; ++i) {
            const float2 pt = bxy[i];
            const float dx = qx - pt.x;
            const float dy = qy - pt.y;
            tk.push(fmaf(dx, dx, dy * dy), i);
        }
    };
    auto row_span = [&](int y, int x0, int x1) {
        if (y < 0 || y >= G) return;
        x0 = max(x0, 0); x1 = min(x1, G - 1);
        if (x0 > x1) return;
        scan_span((int)sCS[y * G + x0], (int)sCS[y * G + x1 + 1]);
    };

    // r=1 block (3x3)
    row_span(cy - 1, cx - 1, cx + 1);
    row_span(cy,     cx - 1, cx + 1);
    row_span(cy + 1, cx - 1, cx + 1);

    bool done = false;
    int r = 1;
    while (true) {
        const float dl = (cx - r >= 0) ? fmaxf(qx - (GMIN + (float)(cx - r) * CW), 0.0f) : FBIG;
        const float dr = (cx + r <  G) ? fmaxf((GMIN + (float)(cx + r + 1) * CW) - qx, 0.0f) : FBIG;
        const float db = (cy - r >= 0) ? fmaxf(qy - (GMIN + (float)(cy - r) * CW), 0.0f) : FBIG;
        const float dt = (cy + r <  G) ? fmaxf((GMIN + (float)(cy + r + 1) * CW) - qy, 0.0f) : FBIG;
        const float dmin = fminf(fminf(dl, dr), fminf(db, dt));
        if (tk.dw < FBIG && tk.dw <= dmin * dmin) { done = true; break; }
        if (r == RCAP) break;
        ++r;
        row_span(cy - r, cx - r, cx + r);
        row_span(cy + r, cx - r, cx + r);
        for (int y = cy - r + 1; y <= cy + r - 1; ++y) {
            if (y < 0 || y >= G) continue;
            if (cx - r >= 0) scan_span((int)sCS[y * G + cx - r], (int)sCS[y * G + cx - r + 1]);
            if (cx + r <  G) scan_span((int)sCS[y * G + cx + r], (int)sCS[y * G + cx + r + 1]);
        }
    }

    if (done) {
#pragma unroll
        for (int s = 0; s < KNB; ++s) nb[p * KNB + s] = tk.id[s];
    } else {
        const int slot = atomicAdd(scnt, 1);
        slist[slot] = p;
    }
}

// ---------------------------------------------------------------------------
// Straggler pass: one 64-lane WAVE per straggler point, brute force over all
// 16384 candidates (stride-64 disjoint partition -> duplicate-free butterfly
// merge; coalesced float2 loads). Grid-stride over the device-side count.
// Worst case (all points stragglers) is still bounded (~16 pts/wave).
// ---------------------------------------------------------------------------
__global__ __launch_bounds__(256) void knn_brute(const float2* __restrict__ bxy,
                                                 const int* __restrict__ scnt,
                                                 const int* __restrict__ slist,
                                                 int* __restrict__ nb) {
    const int lane   = threadIdx.x & 63;
    const int wave   = (blockIdx.x * 256 + threadIdx.x) >> 6;
    const int nwaves = (gridDim.x * 256) >> 6;
    const int n = scnt[0];

    for (int w = wave; w < n; w += nwaves) {
        const int p = slist[w];
        const float2 q = bxy[p];
        TopK tk; tk.init();
        for (int i = lane; i < NPTS; i += 64) {
            const float2 pt = bxy[i];
            const float dx = q.x - pt.x;
            const float dy = q.y - pt.y;
            tk.push(fmaf(dx, dx, dy * dy), i);
        }
#pragma unroll
        for (int m = 1; m < 64; m <<= 1) {
            float od[KNB]; int oid[KNB];
#pragma unroll
            for (int s = 0; s < KNB; ++s) {
                od[s]  = __shfl_xor(tk.d[s], m);
                oid[s] = __shfl_xor(tk.id[s], m);
            }
#pragma unroll
            for (int s = 0; s < KNB; ++s) tk.push(od[s], oid[s]);
        }
        if (lane == 0) {
#pragma unroll
            for (int s = 0; s < KNB; ++s) nb[p * KNB + s] = tk.id[s];
        }
    }
}

// ---------------------------------------------------------------------------
// GCN layer in binned order, thread per point, 64 blocks x 256 threads
// (4 waves/CU for gather-latency hiding). FINAL fuses residual and scatters
// back to original order via bid.
// ---------------------------------------------------------------------------
template <int CIN, int COUT, bool RELU, bool FINAL>
__global__ __launch_bounds__(256) void gcn_layer(const float* __restrict__ hin,
                                                 const int* __restrict__ nb,
                                                 const float* __restrict__ W,
                                                 const float* __restrict__ xb,
                                                 const int* __restrict__ bid,
                                                 float* __restrict__ hout) {
    const int n = blockIdx.x * 256 + threadIdx.x;

    float agg[CIN];
#pragma unroll
    for (int c = 0; c < CIN; ++c) agg[c] = 0.0f;

#pragma unroll
    for (int k = 0; k < KNB; ++k) {
        const int j = nb[n * KNB + k];
        const float4* r = reinterpret_cast<const float4*>(hin + (size_t)j * CIN);
#pragma unroll
        for (int c4 = 0; c4 < CIN / 4; ++c4) {
            const float4 v = r[c4];
            agg[4 * c4 + 0] += v.x;
            agg[4 * c4 + 1] += v.y;
            agg[4 * c4 + 2] += v.z;
            agg[4 * c4 + 3] += v.w;
        }
    }
#pragma unroll
    for (int c = 0; c < CIN; ++c) agg[c] *= (1.0f / 9.0f);

    const int outrow = FINAL ? bid[n] : n;
#pragma unroll
    for (int o = 0; o < COUT; ++o) {
        float acc = 0.0f;
#pragma unroll
        for (int c = 0; c < CIN; ++c) acc = fmaf(agg[c], W[c * COUT + o], acc);
        if (RELU)  acc = fmaxf(acc, 0.0f);
        if (FINAL) acc = xb[n * COUT + o] + 1e-4f * acc;
        hout[outrow * COUT + o] = acc;
    }
}

// ---------------------------------------------------------------------------
extern "C" void kernel_launch(void* const* d_in, const int* in_sizes, int n_in,
                              void* d_out, int out_size, void* d_ws, size_t ws_size,
                              hipStream_t stream) {
    const float* seed = (const float*)d_in[0];
    const float* W1   = (const float*)d_in[1];
    const float* W2   = (const float*)d_in[2];
    const float* W3   = (const float*)d_in[3];
    const float* W4   = (const float*)d_in[4];
    float* out = (float*)d_out;

    char* ws = (char*)d_ws;
    size_t off = 0;
    auto alloc = [&](size_t bytes) -> void* {
        void* p = ws + off;
        off += (bytes + 255) & ~(size_t)255;
        return p;
    };
    int*            cnt    = (int*)   alloc(GC * sizeof(int));
    unsigned short* cs16   = (unsigned short*)alloc((GC + 2) * sizeof(unsigned short));
    int*            cursor = (int*)   alloc(GC * sizeof(int));
    int*            cellOf = (int*)   alloc(NPTS * sizeof(int));
    float2*         bxy    = (float2*)alloc((size_t)NPTS * sizeof(float2));
    int*            bid    = (int*)   alloc(NPTS * sizeof(int));
    float*          xb     = (float*) alloc((size_t)NPTS * CDIM * sizeof(float));
    int*            nb     = (int*)   alloc((size_t)NPTS * KNB * sizeof(int));
    float*          hA     = (float*) alloc((size_t)NPTS * HDIM * sizeof(float));
    float*          hB     = (float*) alloc((size_t)NPTS * HDIM * sizeof(float));
    float*          x1     = (float*) alloc((size_t)NPTS * CDIM * sizeof(float));
    int*            scnt   = (int*)   alloc(256);
    int*            slist  = (int*)   alloc(NPTS * sizeof(int));

    constexpr int NB64 = NPTS / 64;     // 256 blocks of 64

    // cnt must be zero before step-0 bin_count (ws is poisoned each call);
    // scan_kernel re-zeros it for step 1 and zeroes scnt each step.
    hipMemsetAsync(cnt, 0, GC * sizeof(int), stream);

    for (int step = 0; step < 2; ++step) {
        const float* xin  = (step == 0) ? seed : x1;
        float*       xout = (step == 0) ? x1   : out;

        bin_count     <<<NB64, 64, 0, stream>>>(xin, cnt, cellOf);
        scan_kernel   <<<1, 1024, 0, stream>>>(cnt, cs16, cursor, scnt);
        scatter_kernel<<<NB64, 64, 0, stream>>>(xin, cellOf, cursor, bxy, bid, xb);
        knn_search    <<<64, 256, 0, stream>>>(bxy, cs16, nb, scnt, slist);
        knn_brute     <<<64, 256, 0, stream>>>(bxy, scnt, slist, nb);

        gcn_layer<CDIM, HDIM, true,  false><<<64, 256, 0, stream>>>(xb, nb, W1, nullptr, nullptr, hA);
        gcn_layer<HDIM, HDIM, true,  false><<<64, 256, 0, stream>>>(hA, nb, W2, nullptr, nullptr, hB);
        gcn_layer<HDIM, HDIM, true,  false><<<64, 256, 0, stream>>>(hB, nb, W3, nullptr, nullptr, hA);
        gcn_layer<HDIM, CDIM, false, true ><<<64, 256, 0, stream>>>(hA, nb, W4, xb, bid, xout);
    }
}